// Round 4
// baseline (27.137 us; speedup 1.0000x reference)
//
#include <hip/hip_runtime.h>
#include <hip/hip_bf16.h>
#include <math.h>

// Camera folds to: screen X = vz*inv, Y = vy*inv, inv = 1/((2.732-vx)*tan30+EPS)
#define FEPS   1e-8f
#define TANV   0.57735026918962576f   // tan(30 deg)
#define SCL    144.26950408889634f    // (1/SIGMA=100)*log2(e): log2-domain prescale
#define CLIP2  19.931568569324174f    // -log(1e-6)/ln2
#define TFAR   -20.0f                 // skip if contribution < ~1e-6 nats
#define EYEX   2.732f
#define PXD    0.0078125f             // 2/256
#define NFACE  512
#define WX     0.05859375f            // 7.5*PXD : x half-span of a 16-px tile
#define WY     0.01171875f            // 1.5*PXD : y half-span of a 4-row tile

// Single fused kernel. 1024 blocks x 256 thr. Block = 16x4 pixel tile.
// Wave q owns faces [q*128,(q+1)*128): each lane derives 2 faces' edge coeffs
// from verts (registers), writes them to LDS, classifies its faces vs the tile
// (far / saturated-inside / band), then all 64 lanes (1 lane = 1 pixel) walk
// the wave-uniform band list two faces at a time.
__global__ __launch_bounds__(256) void sil_kernel(
    const float* __restrict__ verts, const int* __restrict__ faces,
    const float* __restrict__ ref, float* __restrict__ out)
{
    __shared__ float4 sf[NFACE * 3];
    __shared__ float red[64][5];

    const int tid = threadIdx.x, lane = tid & 63, q = tid >> 6;
    const int tileX = blockIdx.x & 15, tileY = blockIdx.x >> 4;
    const int col0 = tileX << 4, row0 = tileY << 2;

    const float pxc = (float)(col0 + 8) * PXD - 1.0f;   // tile center
    const float pyc = 1.0f - (float)(row0 + 2) * PXD;

    // ---- fused prep + classification (lane = face) ----
    unsigned long long bmask[2];
    int incnt = 0;
#pragma unroll
    for (int k = 0; k < 2; ++k) {
        const int f = q * 128 + k * 64 + lane;
        const int ii[3] = { faces[3*f], faces[3*f+1], faces[3*f+2] };
        float X[3], Y[3];
#pragma unroll
        for (int v = 0; v < 3; ++v) {
            const float vx = verts[3*ii[v]+0];
            const float vy = verts[3*ii[v]+1];
            const float vz = verts[3*ii[v]+2];
            const float inv = __builtin_amdgcn_rcpf(fmaf(EYEX - vx, TANV, FEPS));
            X[v] = vz * inv;
            Y[v] = vy * inv;
        }
        const float area = (X[1]-X[0])*(Y[2]-Y[0]) - (Y[1]-Y[0])*(X[2]-X[0]);
        const float sgn  = (area >= 0.0f) ? SCL : -SCL;
        float lo = 1e30f, hi = 1e30f;
#pragma unroll
        for (int e = 0; e < 3; ++e) {
            const int   e1 = (e == 2) ? 0 : e + 1;
            const float ex = X[e1] - X[e], ey = Y[e1] - Y[e];
            const float il = __builtin_amdgcn_rsqf(fmaf(ex,ex,fmaf(ey,ey,FEPS))) * sgn;
            const float A = -ey * il;
            const float B =  ex * il;
            const float C = (ey * X[e] - ex * Y[e]) * il;
            sf[f*3 + e] = make_float4(A, B, C, 0.0f);
            const float u = fmaf(A, pxc, fmaf(B, pyc, C));
            const float w = fabsf(A) * WX + fabsf(B) * WY;
            lo = fminf(lo, u - w);
            hi = fminf(hi, u + w);
        }
        const bool inside = (lo >= CLIP2);          // clipped everywhere: exact CLIP2
        const bool band   = (!inside) && (hi > TFAR);
        bmask[k] = __ballot(band);
        incnt += __popcll(__ballot(inside));
    }
    __syncthreads();

    // ---- band walk (lane = pixel), 2 faces/iter for trans-pipe ILP ----
    const int   col = col0 + (lane & 15), row = row0 + (lane >> 4);
    const float px  = ((float)col + 0.5f) * PXD - 1.0f;
    const float py  = 1.0f - ((float)row + 0.5f) * PXD;
    float acc = (float)incnt * CLIP2;

    unsigned long long m0 = bmask[0], m1 = bmask[1];
    const int base = q * 128;
#define POP(F) { if (m0) { F = base + (int)__builtin_ctzll(m0); m0 &= m0-1; } \
                 else if (m1) { F = base + 64 + (int)__builtin_ctzll(m1); m1 &= m1-1; } \
                 else F = -1; }
    int fa, fb;
    POP(fa); POP(fb);
    int faL = fa < 0 ? 0 : fa, fbL = fb < 0 ? 0 : fb;
    float4 A0 = sf[faL*3], A1 = sf[faL*3+1], A2 = sf[faL*3+2];
    float4 B0 = sf[fbL*3], B1 = sf[fbL*3+1], B2 = sf[fbL*3+2];
    while (fa >= 0) {
        int fc, fd2;
        POP(fc); POP(fd2);
        const int fcL = fc < 0 ? 0 : fc, fdL = fd2 < 0 ? 0 : fd2;
        float4 C0 = sf[fcL*3], C1 = sf[fcL*3+1], C2 = sf[fcL*3+2];  // prefetch
        float4 D0 = sf[fdL*3], D1 = sf[fdL*3+1], D2 = sf[fdL*3+2];
        const float ua = fminf(fminf(fmaf(A0.x,px,fmaf(A0.y,py,A0.z)),
                                     fmaf(A1.x,px,fmaf(A1.y,py,A1.z))),
                                     fmaf(A2.x,px,fmaf(A2.y,py,A2.z)));
        const float ub = fminf(fminf(fmaf(B0.x,px,fmaf(B0.y,py,B0.z)),
                                     fmaf(B1.x,px,fmaf(B1.y,py,B1.z))),
                                     fmaf(B2.x,px,fmaf(B2.y,py,B2.z)));
        const float ca = fminf(__builtin_amdgcn_logf(1.0f + __builtin_amdgcn_exp2f(ua)), CLIP2);
        const float cb = fminf(__builtin_amdgcn_logf(1.0f + __builtin_amdgcn_exp2f(ub)), CLIP2);
        acc += ca;
        acc += (fb >= 0) ? cb : 0.0f;
        fa = fc; fb = fd2;
        A0 = C0; A1 = C1; A2 = C2;
        B0 = D0; B1 = D1; B2 = D2;
    }
#undef POP

    red[lane][q] = acc;
    __syncthreads();

    // ---- per-pixel silhouette + squared-error, block reduce, one atomic ----
    if (tid < 64) {
        const float S   = red[tid][0] + red[tid][1] + red[tid][2] + red[tid][3];
        const float sil = 1.0f - __builtin_amdgcn_exp2f(-S);
        const int prow = row0 + (tid >> 4), pcol = col0 + (tid & 15);
        const float d  = sil - ref[prow * 256 + pcol];
        float v = d * d;
#pragma unroll
        for (int off = 32; off > 0; off >>= 1)
            v += __shfl_down(v, off);
        if (tid == 0) atomicAdd(out, v);
    }
}

extern "C" void kernel_launch(void* const* d_in, const int* in_sizes, int n_in,
                              void* d_out, int out_size, void* d_ws, size_t ws_size,
                              hipStream_t stream) {
    const float* verts = (const float*)d_in[0];   // (1,4096,3) f32
    const int*   faces = (const int*)d_in[1];     // (1,512,3) i32
    const float* ref   = (const float*)d_in[2];   // (256,256) f32
    float*       out   = (float*)d_out;           // scalar loss

    hipMemsetAsync(d_out, 0, sizeof(float), stream);
    sil_kernel<<<1024, 256, 0, stream>>>(verts, faces, ref, out);
}